// Round 6
// baseline (492.152 us; speedup 1.0000x reference)
//
#include <hip/hip_runtime.h>
#include <stdint.h>

#define NN 8192
#define IN_DIM 32
#define HID_DIM 64
#define OUT_DIM 16

typedef __attribute__((ext_vector_type(8))) short short8;
typedef __attribute__((ext_vector_type(4))) float f32x4;

// fp32 -> bf16 bits, round-to-nearest-even
__device__ __forceinline__ short f2bf_bits(float x){
  uint32_t u = __builtin_bit_cast(uint32_t, x);
  u += 0x7FFFu + ((u >> 16) & 1u);
  return (short)(u >> 16);
}

__device__ __forceinline__ short8 cvt8(f32x4 lo, f32x4 hi){
  short8 r;
  r[0]=f2bf_bits(lo[0]); r[1]=f2bf_bits(lo[1]); r[2]=f2bf_bits(lo[2]); r[3]=f2bf_bits(lo[3]);
  r[4]=f2bf_bits(hi[0]); r[5]=f2bf_bits(hi[1]); r[6]=f2bf_bits(hi[2]); r[7]=f2bf_bits(hi[3]);
  return r;
}

// Kernel 0: Gt[c][r] = bf16( (X @ W1)[r][c] )   [64][8192]
__global__ __launch_bounds__(256) void k_g(const float* __restrict__ X, const float* __restrict__ W1,
                                           short* __restrict__ Gt){
  const int b    = blockIdx.x;
  const int rb   = (b & 127) * 64;
  const int cg   = b >> 7;
  const int lane = threadIdx.x & 63;
  const int c    = cg * 4 + (threadIdx.x >> 6);
  const int r    = rb + lane;
  const float* xr = X + (size_t)r * IN_DIM;
  float acc = 0.f;
  #pragma unroll
  for (int k = 0; k < IN_DIM; ++k)
    acc += xr[k] * W1[(size_t)k * HID_DIM + c];
  Gt[(size_t)c * NN + r] = f2bf_bits(acc);
}

// mm_row: P[rows][0..63] += adj[rows][krange] @ Bt^T for ONE adjacency matrix
// (blockIdx.z selects adj1/adj2). M-tile = 64 rows, K-group = 256 cols.
// Staging: one wave-instr = ONE row x 1 KB contiguous (64 lanes x 16 B) --
// long sequential DRAM runs. Per-block skewed K-group order de-synchronizes
// blocks' column phases. Granule-XOR swizzle applied at the GLOBAL source
// (LDS dest linear, m104/m173); compute reads granule g ^ (row&15) -> 2-way
// max bank aliasing (free, m136). LDS 2 x 64 KB = 128 KB -> 1 block/CU.
template<int REV>
__global__ __launch_bounds__(256) void mm_row(const float* __restrict__ adj1, const float* __restrict__ adj2,
                                              const short* __restrict__ Bt,
                                              float* __restrict__ P1, float* __restrict__ P2, int klen){
  __shared__ __align__(16) float sA[2][64 * 256];
  const int tid  = threadIdx.x;
  const int lane = tid & 63;
  const int wave = tid >> 6;
  const int bm   = REV ? ((int)gridDim.x - 1 - (int)blockIdx.x) : (int)blockIdx.x;
  const int ks   = REV ? ((int)gridDim.y - 1 - (int)blockIdx.y) : (int)blockIdx.y;
  const float* __restrict__ adj = blockIdx.z ? adj2 : adj1;
  const int k0   = ks * klen;
  const int ngrp = klen >> 8;                 // 256-col groups (klen=2048 -> 8)
  const int skew = bm & (ngrp - 1);
  const size_t growb = (size_t)(bm * 64) * NN;

  const int rl = lane & 15;                   // row-within-strip and D-col
  const int qh = lane >> 4;

  // group visited at time t: fwd = (skew+t)%ngrp, rev = exact temporal reverse
  auto gat = [&](int t){
    int s = REV ? (skew + ngrp - 1 - t) : (skew + t);
    return s & (ngrp - 1);
  };

  auto stage = [&](int t){
    const int g   = gat(t);
    const int buf = t & 1;
    const size_t colb = (size_t)(k0 + g * 256);
    #pragma unroll
    for (int p = 0; p < 16; ++p){
      const int row = p * 4 + wave;           // 0..63, uniform per wave-instr
      const int key = row & 15;
      const float* src = adj + growb + (size_t)row * NN + colb + ((lane ^ key) << 2);
      __builtin_amdgcn_global_load_lds(
          (const __attribute__((address_space(1))) void*)src,
          (__attribute__((address_space(3))) void*)&sA[buf][row * 256 + lane * 4], 16, 0, 0);
    }
  };

  f32x4 acc[4] = {{0,0,0,0},{0,0,0,0},{0,0,0,0},{0,0,0,0}};

  stage(0);
  __syncthreads();

  #pragma unroll 1
  for (int t = 0; t < ngrp; ++t){
    if (t + 1 < ngrp) stage(t + 1);           // in flight under compute + drain
    const int g     = gat(t);
    const int buf   = t & 1;
    const int kbase = k0 + g * 256;
    const int rbase = (wave * 16 + rl) * 256;
    #pragma unroll
    for (int j = 0; j < 8; ++j){
      const int g0 = j * 8 + qh * 2;
      f32x4 lo = *(const f32x4*)&sA[buf][rbase + (((g0    ) ^ rl) << 2)];
      f32x4 hi = *(const f32x4*)&sA[buf][rbase + (((g0 + 1) ^ rl) << 2)];
      short8 b[4];
      const size_t bk = (size_t)kbase + j * 32 + qh * 8;
      #pragma unroll
      for (int f = 0; f < 4; ++f)
        b[f] = *(const short8*)(Bt + (size_t)(f * 16 + rl) * NN + bk);
      short8 fa = cvt8(lo, hi);
      #pragma unroll
      for (int f = 0; f < 4; ++f)
        acc[f] = __builtin_amdgcn_mfma_f32_16x16x32_bf16(fa, b[f], acc[f], 0, 0, 0);
    }
    __syncthreads();                          // drains stage(t+1), WAR guard
  }

  // D layout: col = lane&15, row = (lane>>4)*4 + reg
  const int orow = bm * 64 + wave * 16 + qh * 4;
  float* P = blockIdx.z ? P2 : P1;
  float* p = P + ((size_t)ks * NN + orow) * HID_DIM + rl;
  #pragma unroll
  for (int r = 0; r < 4; ++r){
    #pragma unroll
    for (int f = 0; f < 4; ++f)
      p[(size_t)r * HID_DIM + f * 16] = acc[f][r];
  }
}

// l1_combine: H1t[c][r] = bf16( relu(SY1+b1) + relu(SY2+b1) ), LDS transpose
__global__ __launch_bounds__(256) void l1_combine(const float* __restrict__ Y1p, const float* __restrict__ Y2p,
                                                  const float* __restrict__ b1,
                                                  short* __restrict__ H1t, int S){
  __shared__ float sH[64][65];
  const int tid = threadIdx.x, lane = tid & 63, wave = tid >> 6;
  const int rb = blockIdx.x * 64;
  const float bc = b1[lane];
  #pragma unroll 4
  for (int rq = 0; rq < 16; ++rq){
    const int r = rq * 4 + wave;
    const int row = rb + r;
    float s1 = 0.f, s2 = 0.f;
    for (int sp = 0; sp < S; ++sp){
      s1 += Y1p[((size_t)sp * NN + row) * HID_DIM + lane];
      s2 += Y2p[((size_t)sp * NN + row) * HID_DIM + lane];
    }
    sH[r][lane] = fmaxf(s1 + bc, 0.f) + fmaxf(s2 + bc, 0.f);
  }
  __syncthreads();
  #pragma unroll 4
  for (int i = 0; i < 16; ++i){
    const int c = wave * 16 + i;
    H1t[(size_t)c * NN + rb + lane] = f2bf_bits(sH[lane][c]);
  }
}

// l2_combine: out[row][c] = relu(Z1@W2+b2) + relu(Z2@W2+b2)
__global__ __launch_bounds__(256) void l2_combine(const float* __restrict__ Z1p, const float* __restrict__ Z2p,
                                                  const float* __restrict__ W2, const float* __restrict__ b2,
                                                  float* __restrict__ out, int S){
  __shared__ float sW[HID_DIM * OUT_DIM];
  __shared__ float sb[OUT_DIM];
  __shared__ float sz[4][2][HID_DIM];
  const int tid = threadIdx.x;
  for (int i = tid; i < HID_DIM * OUT_DIM; i += 256) sW[i] = W2[i];
  if (tid < OUT_DIM) sb[tid] = b2[tid];
  const int sub = tid >> 6, t = tid & 63;
  const int row = blockIdx.x * 4 + sub;
  float s1 = 0.f, s2 = 0.f;
  for (int sp = 0; sp < S; ++sp){
    s1 += Z1p[((size_t)sp * NN + row) * HID_DIM + t];
    s2 += Z2p[((size_t)sp * NN + row) * HID_DIM + t];
  }
  sz[sub][0][t] = s1;
  sz[sub][1][t] = s2;
  __syncthreads();
  if (t < OUT_DIM){
    float a = sb[t], b = sb[t];
    #pragma unroll
    for (int k = 0; k < HID_DIM; ++k){
      a += sz[sub][0][k] * sW[k * OUT_DIM + t];
      b += sz[sub][1][k] * sW[k * OUT_DIM + t];
    }
    out[(size_t)row * OUT_DIM + t] = fmaxf(a, 0.f) + fmaxf(b, 0.f);
  }
}

extern "C" void kernel_launch(void* const* d_in, const int* in_sizes, int n_in,
                              void* d_out, int out_size, void* d_ws, size_t ws_size,
                              hipStream_t stream){
  const float* adj1 = (const float*)d_in[0];
  const float* adj2 = (const float*)d_in[1];
  const float* X    = (const float*)d_in[2];
  const float* W1   = (const float*)d_in[3];
  const float* b1   = (const float*)d_in[4];
  const float* W2   = (const float*)d_in[5];
  const float* b2   = (const float*)d_in[6];
  float* out = (float*)d_out;

  char* ws = (char*)d_ws;
  short* Gt  = (short*)ws;                           // 64*8192*2 = 1 MB
  short* H1t = (short*)(ws + (size_t)1024 * 1024);   // 1 MB
  const size_t off = (size_t)2 * 1024 * 1024;

  int S = 4;
  while (S > 1 && off + (size_t)S * 4 * 1024 * 1024 > ws_size) S >>= 1;
  float* P1 = (float*)(ws + off);
  float* P2 = P1 + (size_t)S * NN * HID_DIM;
  const int klen = NN / S;

  k_g        <<<dim3(2048),          dim3(256), 0, stream>>>(X, W1, Gt);
  mm_row<0>  <<<dim3(NN / 64, S, 2), dim3(256), 0, stream>>>(adj1, adj2, Gt, P1, P2, klen);
  l1_combine <<<dim3(NN / 64),       dim3(256), 0, stream>>>(P1, P2, b1, H1t, S);
  mm_row<1>  <<<dim3(NN / 64, S, 2), dim3(256), 0, stream>>>(adj1, adj2, H1t, P1, P2, klen);
  l2_combine <<<dim3(NN / 4),        dim3(256), 0, stream>>>(P1, P2, W2, b2, out, S);
}